// Round 2
// baseline (496.524 us; speedup 1.0000x reference)
//
#include <hip/hip_runtime.h>

typedef __bf16 bf16_t;
typedef __bf16 bf16x8 __attribute__((ext_vector_type(8)));
typedef __bf16 bf16x4 __attribute__((ext_vector_type(4)));
typedef float f32x4 __attribute__((ext_vector_type(4)));

#define DM 768
#define SEQ_LEN 4096
#define TOKENS 32768

// async 16B global -> LDS (wave-uniform LDS base + lane*16)
__device__ __forceinline__ void load16_to_lds(const void* g, void* l) {
  __builtin_amdgcn_global_load_lds(
      (const __attribute__((address_space(1))) unsigned int*)g,
      (__attribute__((address_space(3))) unsigned int*)l, 16, 0, 0);
}

// ---------------- weight cast / transpose ----------------
__global__ __launch_bounds__(256)
void cast_transpose_kernel(const float* __restrict__ W, bf16_t* __restrict__ WT,
                           int K, int N, int stride, int off) {
  long idx = (long)blockIdx.x * 256 + threadIdx.x;
  if (idx >= (long)K * N) return;
  int n = (int)(idx / K);
  int k = (int)(idx % K);
  WT[idx] = (bf16_t)W[(long)k * stride + off + n];
}

// a[k] = -sum_d exp(A_log[k,d]) ; b[k] = sum_{d<16} W_x[k,d]
__global__ __launch_bounds__(256)
void ab_kernel(const float* __restrict__ Wx, const float* __restrict__ A_log,
               float* __restrict__ a_vec, float* __restrict__ b_vec) {
  int k = blockIdx.x * 256 + threadIdx.x;
  if (k >= DM) return;
  float a = 0.f, b = 0.f;
#pragma unroll
  for (int d = 0; d < 16; d++) {
    a -= __expf(A_log[k * 16 + d]);
    b += Wx[(long)k * 784 + d];
  }
  a_vec[k] = a;
  b_vec[k] = b;
}

// ---------------- layernorm -> bf16 (token per wave, float4) ----------------
__global__ __launch_bounds__(256)
void ln_kernel(const float* __restrict__ x, const float* __restrict__ gamma,
               const float* __restrict__ beta, bf16_t* __restrict__ xn) {
  const int tok = blockIdx.x * 4 + (threadIdx.x >> 6);
  const int lane = threadIdx.x & 63;
  const float4* xr = (const float4*)(x + (long)tok * DM);
  float4 v0 = xr[lane], v1 = xr[lane + 64], v2 = xr[lane + 128];
  float s = v0.x + v0.y + v0.z + v0.w + v1.x + v1.y + v1.z + v1.w +
            v2.x + v2.y + v2.z + v2.w;
  float ss = v0.x * v0.x + v0.y * v0.y + v0.z * v0.z + v0.w * v0.w +
             v1.x * v1.x + v1.y * v1.y + v1.z * v1.z + v1.w * v1.w +
             v2.x * v2.x + v2.y * v2.y + v2.z * v2.z + v2.w * v2.w;
  for (int o = 1; o < 64; o <<= 1) { s += __shfl_xor(s, o); ss += __shfl_xor(ss, o); }
  float mu = s * (1.0f / DM);
  float var = ss * (1.0f / DM) - mu * mu;
  float inv = rsqrtf(var + 1e-5f);
  const float4* g4 = (const float4*)gamma;
  const float4* b4 = (const float4*)beta;
  bf16_t* xo = xn + (long)tok * DM;
#pragma unroll
  for (int i = 0; i < 3; i++) {
    float4 v = (i == 0) ? v0 : (i == 1) ? v1 : v2;
    float4 g = g4[lane + 64 * i], b = b4[lane + 64 * i];
    bf16x4 o;
    o[0] = (bf16_t)((v.x - mu) * inv * g.x + b.x);
    o[1] = (bf16_t)((v.y - mu) * inv * g.y + b.y);
    o[2] = (bf16_t)((v.z - mu) * inv * g.z + b.z);
    o[3] = (bf16_t)((v.w - mu) * inv * g.w + b.w);
    *(bf16x4*)(xo + lane * 4 + i * 256) = o;
  }
}

// ---------------- depthwise causal conv (4 taps) + hs (token per wave) -------
__global__ __launch_bounds__(256)
void conv_kernel(const bf16_t* __restrict__ xz, const float* __restrict__ conv_w,
                 const float* __restrict__ a_vec, const float* __restrict__ b_vec,
                 bf16_t* __restrict__ x1, float* __restrict__ hs) {
  const int tok = blockIdx.x * 4 + (threadIdx.x >> 6);
  const int lane = threadIdx.x & 63;
  const int l = tok & (SEQ_LEN - 1);
  const bf16_t* base = xz + (long)tok * 1536;
  const float4* w4 = (const float4*)conv_w;
  float s = 0.f, sa = 0.f, sb = 0.f;

  // region 1: channels lane*8 .. lane*8+7 (512 channels)
  {
    const int c0 = lane * 8;
    bf16x8 cur = *(const bf16x8*)(base + c0);
    bf16x8 p1 = {}, p2 = {}, p3 = {};
    if (l >= 1) p1 = *(const bf16x8*)(base + c0 - 1536);
    if (l >= 2) p2 = *(const bf16x8*)(base + c0 - 2 * 1536);
    if (l >= 3) p3 = *(const bf16x8*)(base + c0 - 3 * 1536);
    bf16x8 o;
#pragma unroll
    for (int j = 0; j < 8; j++) {
      float4 w = w4[c0 + j];
      float acc = w.w * (float)cur[j] + w.z * (float)p1[j] +
                  w.y * (float)p2[j] + w.x * (float)p3[j];
      bf16_t xb = (bf16_t)acc;
      o[j] = xb;
      float xv = (float)xb;
      s += xv; sa += xv * a_vec[c0 + j]; sb += xv * b_vec[c0 + j];
    }
    *(bf16x8*)(x1 + (long)tok * DM + c0) = o;
  }
  // region 2: channels 512 + lane*4 .. +3 (256 channels)
  {
    const int c0 = 512 + lane * 4;
    bf16x4 cur = *(const bf16x4*)(base + c0);
    bf16x4 p1 = {}, p2 = {}, p3 = {};
    if (l >= 1) p1 = *(const bf16x4*)(base + c0 - 1536);
    if (l >= 2) p2 = *(const bf16x4*)(base + c0 - 2 * 1536);
    if (l >= 3) p3 = *(const bf16x4*)(base + c0 - 3 * 1536);
    bf16x4 o;
#pragma unroll
    for (int j = 0; j < 4; j++) {
      float4 w = w4[c0 + j];
      float acc = w.w * (float)cur[j] + w.z * (float)p1[j] +
                  w.y * (float)p2[j] + w.x * (float)p3[j];
      bf16_t xb = (bf16_t)acc;
      o[j] = xb;
      float xv = (float)xb;
      s += xv; sa += xv * a_vec[c0 + j]; sb += xv * b_vec[c0 + j];
    }
    *(bf16x4*)(x1 + (long)tok * DM + c0) = o;
  }
  for (int o = 1; o < 64; o <<= 1) {
    s += __shfl_xor(s, o); sa += __shfl_xor(sa, o); sb += __shfl_xor(sb, o);
  }
  if (lane == 0) hs[tok] = sa + s * sb;
}

// ---------------- 128x128 MFMA GEMM (m97-class, proven-best tile) ----------
// C[M,N] = A[M,K] @ BT[N,K]^T ; 4 waves, wave-tile 64x64, acc 4x4 of 16x16.
// 1D grid with bijective XCD swizzle (nwg % 8 == 0), by-fastest within chunk
// so each XCD keeps one A-tile + all B-panels L2-resident.
// OUT_MODE 0: bf16 out
// OUT_MODE 1: fused SSM epilogue -> y bf16
// OUT_MODE 2: f32 out + residual add
template <int OUT_MODE>
__global__ __launch_bounds__(256, 3)
void gemm128_kernel(const bf16_t* __restrict__ A, const bf16_t* __restrict__ BT,
                    void* __restrict__ outp, const float* __restrict__ res,
                    const bf16_t* __restrict__ x1, const bf16_t* __restrict__ xz,
                    const float* __restrict__ hs, const float* __restrict__ Dp,
                    int M, int N, int K) {
  __shared__ __align__(16) bf16_t As[128 * 32];  // 8 KB
  __shared__ __align__(16) bf16_t Bs[128 * 32];  // 8 KB

  const int nby = N >> 7;
  const int nwg = (M >> 7) * nby;
  const int cpx = nwg >> 3;                       // blocks per XCD chunk
  const int wg = blockIdx.x;
  const int swz = (wg & 7) * cpx + (wg >> 3);     // bijective (nwg % 8 == 0)
  const int bx = swz / nby;                       // by varies fastest in-chunk
  const int by = swz - bx * nby;
  const int m0 = bx << 7;
  const int n0 = by << 7;

  const int t = threadIdx.x;
  const int lane = t & 63;
  const int wave = t >> 6;
  const int wm = (wave >> 1) * 64;
  const int wn = (wave & 1) * 64;
  const int l15 = lane & 15;
  const int quad = lane >> 4;

  f32x4 acc[4][4] = {};

  // staging: 512-elem chunks (64 lanes x 16B = 16 rows x 32 cols). 8 chunks each.
  const int sr = lane >> 2;        // row within chunk (16 rows/chunk)
  const int sc = (lane & 3) * 8;   // k-col
  const bf16_t* Ag[2];
  bf16_t* lA[2];
#pragma unroll
  for (int i = 0; i < 2; i++) {
    int ch = wave * 2 + i;
    Ag[i] = A + (long)(m0 + ch * 16 + sr) * K + sc;
    lA[i] = As + ch * 512 + lane * 8;
  }
  const bf16_t* Bg[2];
  bf16_t* lB[2];
#pragma unroll
  for (int i = 0; i < 2; i++) {
    int ch = wave * 2 + i;
    Bg[i] = BT + (long)(n0 + ch * 16 + sr) * K + sc;
    lB[i] = Bs + ch * 512 + lane * 8;
  }

  for (int k0 = 0; k0 < K; k0 += 32) {
#pragma unroll
    for (int i = 0; i < 2; i++) load16_to_lds(Ag[i] + k0, lA[i]);
#pragma unroll
    for (int i = 0; i < 2; i++) load16_to_lds(Bg[i] + k0, lB[i]);
    __syncthreads();
    bf16x8 bfrag[4];
#pragma unroll
    for (int ni = 0; ni < 4; ni++)
      bfrag[ni] = *(const bf16x8*)&Bs[(wn + ni * 16 + l15) * 32 + quad * 8];
#pragma unroll
    for (int mi = 0; mi < 4; mi++) {
      bf16x8 afrag = *(const bf16x8*)&As[(wm + mi * 16 + l15) * 32 + quad * 8];
#pragma unroll
      for (int ni = 0; ni < 4; ni++)
        acc[mi][ni] = __builtin_amdgcn_mfma_f32_16x16x32_bf16(afrag, bfrag[ni], acc[mi][ni], 0, 0, 0);
    }
    __syncthreads();
  }

#pragma unroll
  for (int mi = 0; mi < 4; mi++) {
#pragma unroll
    for (int r = 0; r < 4; r++) {
      const int row = m0 + wm + mi * 16 + quad * 4 + r;
      float hsv = 0.f;
      if (OUT_MODE == 1) hsv = hs[row];
#pragma unroll
      for (int ni = 0; ni < 4; ni++) {
        const int col = n0 + wn + ni * 16 + l15;
        const long o = (long)row * N + col;
        float v = acc[mi][ni][r];
        if (OUT_MODE == 0) {
          ((bf16_t*)outp)[o] = (bf16_t)v;
        } else if (OUT_MODE == 1) {
          float xv = (float)x1[(long)row * DM + col];
          float zv = (float)xz[(long)row * 1536 + DM + col];
          float yv = v * hsv + Dp[col] * xv;
          yv *= zv / (1.f + __expf(-zv));
          ((bf16_t*)outp)[o] = (bf16_t)yv;
        } else {
          ((float*)outp)[o] = v + res[o];
        }
      }
    }
  }
}

// ---------------- launch ----------------
extern "C" void kernel_launch(void* const* d_in, const int* in_sizes, int n_in,
                              void* d_out, int out_size, void* d_ws, size_t ws_size,
                              hipStream_t stream) {
  const float* x      = (const float*)d_in[0];
  const float* W_in   = (const float*)d_in[1];
  const float* conv_w = (const float*)d_in[2];
  const float* W_x    = (const float*)d_in[3];
  const float* A_log  = (const float*)d_in[4];
  const float* Dp     = (const float*)d_in[5];
  const float* W_out  = (const float*)d_in[6];
  const float* gamma  = (const float*)d_in[7];
  const float* beta   = (const float*)d_in[8];
  float* out = (float*)d_out;

  char* ws = (char*)d_ws;
  bf16_t* w_in_T  = (bf16_t*)(ws + 0);          // 1536x768 bf16
  bf16_t* w_c_T   = (bf16_t*)(ws + 2359296);    //  768x768 bf16
  bf16_t* w_out_T = (bf16_t*)(ws + 3538944);    //  768x768 bf16
  float*  a_vec   = (float*)(ws + 4718592);
  float*  b_vec   = (float*)(ws + 4721664);
  float*  hs      = (float*)(ws + 4724736);     // 32768 f32
  bf16_t* xn      = (bf16_t*)(ws + 4855808);    // 32768x768 bf16 (reused as y)
  bf16_t* xz      = (bf16_t*)(ws + 55187456);   // 32768x1536 bf16
  bf16_t* x1      = (bf16_t*)(ws + 155850752);  // 32768x768 bf16
  bf16_t* y       = xn;

  cast_transpose_kernel<<<dim3(1536 * 768 / 256), 256, 0, stream>>>(W_in, w_in_T, 768, 1536, 1536, 0);
  cast_transpose_kernel<<<dim3(768 * 768 / 256), 256, 0, stream>>>(W_x, w_c_T, 768, 768, 784, 16);
  cast_transpose_kernel<<<dim3(768 * 768 / 256), 256, 0, stream>>>(W_out, w_out_T, 768, 768, 768, 0);
  ab_kernel<<<dim3(3), 256, 0, stream>>>(W_x, A_log, a_vec, b_vec);

  ln_kernel<<<dim3(TOKENS / 4), 256, 0, stream>>>(x, gamma, beta, xn);

  // 128x128 tiles: grid = (M/128)*(N/128), 1D with XCD swizzle inside
  gemm128_kernel<0><<<dim3((TOKENS / 128) * (1536 / 128)), 256, 0, stream>>>(
      xn, w_in_T, (void*)xz, nullptr, nullptr, nullptr, nullptr, nullptr,
      TOKENS, 1536, 768);

  conv_kernel<<<dim3(TOKENS / 4), 256, 0, stream>>>(xz, conv_w, a_vec, b_vec, x1, hs);

  gemm128_kernel<1><<<dim3((TOKENS / 128) * (768 / 128)), 256, 0, stream>>>(
      x1, w_c_T, (void*)y, nullptr, x1, xz, hs, Dp,
      TOKENS, 768, 768);

  gemm128_kernel<2><<<dim3((TOKENS / 128) * (768 / 128)), 256, 0, stream>>>(
      y, w_out_T, (void*)out, x, nullptr, nullptr, nullptr, nullptr,
      TOKENS, 768, 768);
}